// Round 4
// baseline (2652.285 us; speedup 1.0000x reference)
//
#include <hip/hip_runtime.h>
#include <math.h>

// Problem constants
#define NTOT 32768   // T*B
#define CIN  201
#define SEQ  67      // keypoints (real seq len); padded to 80 (5 tiles of 16)
#define E    8
#define L    12
#define OUTC 128
#define KF   536     // SEQ*E
#define PWL  512     // packed dwords per layer

// 0.5 (=1/sqrt(DH)) * log2(e) -- folded into packed Q weights/biases
#define QS 0.7213475204444817f

typedef float f32x4 __attribute__((ext_vector_type(4)));
typedef __fp16 h8v  __attribute__((ext_vector_type(8)));
typedef unsigned int u32x4 __attribute__((ext_vector_type(4)));
typedef unsigned int u32x2 __attribute__((ext_vector_type(2)));

#define MFMA16x16x32 __builtin_amdgcn_mfma_f32_16x16x32_f16

__device__ __forceinline__ h8v  bch8(u32x4 u) { return __builtin_bit_cast(h8v, u); }
__device__ __forceinline__ u32x4 bcu4(h8v h)  { return __builtin_bit_cast(u32x4, h); }
__device__ __forceinline__ unsigned pkh(float a, float b) {
    return __builtin_bit_cast(unsigned, __builtin_amdgcn_cvt_pkrtz(a, b));
}

// ---------------------------------------------------------------------------
// Fragment layout assumptions (v_mfma_f32_16x16x32_f16), lane l = tid&63:
//   A[row][k]: row = l&15, k = (l>>4)*8 + r   (r = 0..7, 8 f16 = 4 VGPR)
//   B[k][col]: col = l&15, k = (l>>4)*8 + r
//   C/D:       col = l&15, row = (l>>4)*4 + reg   (verified layout, m89)
// All our K-dims are <=16 real, so only lane-groups g==0 (and g==1 for FF2)
// carry nonzero A/B data; other groups pass zero fragments.
// ---------------------------------------------------------------------------

// Packed per-layer weights (dwords), B-fragment-ordered (lane-major, 4dw/lane):
//   [0..63]    wq0: B[e][o], o=0..15 (Q cols 0-7 prescaled by QS, K cols 8-15)
//   [64..127]  wq1: B[e][o-16] cols 0-7 = V, cols 8-15 zero
//   [128..191] wao: B[e][c] = aow[c][e], cols 8-15 zero
//   [192..255] wf1: B[e][f], f=0..15
//   [256..383] wf2: B[f][c] (g<2 lanes, 32 lanes x 4dw), cols 8-15 zero
//   [384..407] qkvb (Q part x QS) | [408..415] aob | [416..431] f1b
//   [432..439] f2b | [440..447] ln1g | [448..455] ln1b | [456..463] ln2g
//   [464..471] ln2b
__global__ void pack_kernel(const float* __restrict__ ipw, const float* __restrict__ ipb,
                            const float* __restrict__ aow, const float* __restrict__ aob,
                            const float* __restrict__ f1w, const float* __restrict__ f1b,
                            const float* __restrict__ f2w, const float* __restrict__ f2b,
                            const float* __restrict__ g1,  const float* __restrict__ b1,
                            const float* __restrict__ g2,  const float* __restrict__ b2,
                            float* __restrict__ wpk)
{
    const int l = blockIdx.x, t = threadIdx.x;
    float* D = wpk + l * PWL;
    float v = 0.f;
    if (t < 64) {                 // wq0
        int o = t >> 2, d = t & 3;
        float s = (o < 8) ? QS : 1.f;
        v = __builtin_bit_cast(float, pkh(ipw[l*192 + o*8 + 2*d] * s,
                                          ipw[l*192 + o*8 + 2*d + 1] * s));
    } else if (t < 128) {         // wq1 (V)
        int i = t - 64, cc = i >> 2, d = i & 3;
        if (cc < 8)
            v = __builtin_bit_cast(float, pkh(ipw[l*192 + (16+cc)*8 + 2*d],
                                              ipw[l*192 + (16+cc)*8 + 2*d + 1]));
    } else if (t < 192) {         // wao
        int i = t - 128, cc = i >> 2, d = i & 3;
        if (cc < 8)
            v = __builtin_bit_cast(float, pkh(aow[l*64 + cc*8 + 2*d],
                                              aow[l*64 + cc*8 + 2*d + 1]));
    } else if (t < 256) {         // wf1
        int i = t - 192, f = i >> 2, d = i & 3;
        v = __builtin_bit_cast(float, pkh(f1w[l*128 + f*8 + 2*d],
                                          f1w[l*128 + f*8 + 2*d + 1]));
    } else if (t < 384) {         // wf2
        int i = t - 256, l32 = i >> 2, d = i & 3;
        int gq = l32 >> 4, cc = l32 & 15;
        int k = gq*8 + 2*d;       // f index pair
        if (cc < 8)
            v = __builtin_bit_cast(float, pkh(f2w[l*128 + cc*16 + k],
                                              f2w[l*128 + cc*16 + k + 1]));
    }
    else if (t < 408) { int j = t-384; v = ipb[l*24 + j] * ((j < 8) ? QS : 1.f); }
    else if (t < 416) { v = aob[l*8 + (t-408)]; }
    else if (t < 432) { v = f1b[l*16 + (t-416)]; }
    else if (t < 440) { v = f2b[l*8 + (t-432)]; }
    else if (t < 448) { v = g1[l*8 + (t-440)]; }
    else if (t < 456) { v = b1[l*8 + (t-448)]; }
    else if (t < 464) { v = g2[l*8 + (t-456)]; }
    else if (t < 472) { v = b2[l*8 + (t-464)]; }
    D[t] = v;
}

// Per-wave LDS slice (f16 elements):
//   XA [80][16] @0     : x rows (A-frag source); also O rows, post-LN1 x, t1
//   QA [80][8]  @1280  : Q rows (QS prescaled)
//   KB [80][8]  @1920  : K rows
//   VT [8][80]  @2560  : V column-major [vcol][t]
//   PL [16][168]@3200  : P strip (16 s-rows x (t,h)=160, padded to 168 vs banks)
#define WSLICE 5888   // f16 per wave (11776 B); 4 waves = 47104 B

__global__ __launch_bounds__(256, 2)
void enc_kernel(const float* __restrict__ pose,
                const float* __restrict__ ew, const float* __restrict__ ebias,
                const float* __restrict__ wpk,
                float* __restrict__ xf)
{
    __shared__ __fp16 lds[4 * WSLICE];
    const int lid = threadIdx.x & 63;
    const int wv  = threadIdx.x >> 6;
    const int g   = lid >> 4;       // lane group 0..3
    const int c   = lid & 15;       // col / row-within-tile index
    const int n   = blockIdx.x * 4 + wv;

    __fp16* XA = lds + wv * WSLICE;
    __fp16* QA = XA + 1280;
    __fp16* KB = QA + 640;
    __fp16* VT = KB + 640;
    __fp16* PL = VT + 640;

    const h8v zero8 = bch8((u32x4){0u,0u,0u,0u});
    const unsigned ONE2 = 0x3C003C00u;          // two f16 1.0
    const h8v ones8 = bch8((u32x4){ONE2,ONE2,ONE2,ONE2});

    // ---- embed: xc[si][rr] = x[s = si*16+g*4+rr][e = c] (C-layout), c>=8 -> 0
    f32x4 xc[5];
    #pragma unroll
    for (int si = 0; si < 5; ++si) {
        f32x4 v = {0.f,0.f,0.f,0.f};
        if (c < 8) {
            #pragma unroll
            for (int rr = 0; rr < 4; ++rr) {
                int s = si*16 + g*4 + rr;
                if (s < SEQ) {
                    const float* p = pose + (size_t)n*CIN + 3*s;
                    v[rr] = ebias[c] + p[0]*ew[c*3] + p[1]*ew[c*3+1]
                                     + p[2]*ew[c*3+2];
                }
            }
            #pragma unroll
            for (int rr = 0; rr < 4; ++rr)
                XA[(si*16 + g*4 + rr)*16 + c] = (__fp16)v[rr];
        }
        xc[si] = v;
    }

    #pragma unroll 1
    for (int l = 0; l < L; ++l) {
        const float* PW = wpk + l * PWL;

        // weight B-frags (16B per lane, only low groups carry data)
        h8v wq0 = (g==0) ? *(const h8v*)(PW +   0 + c*4) : zero8;
        h8v wq1 = (g==0) ? *(const h8v*)(PW +  64 + c*4) : zero8;
        h8v wao = (g==0) ? *(const h8v*)(PW + 128 + c*4) : zero8;
        h8v wf1 = (g==0) ? *(const h8v*)(PW + 192 + c*4) : zero8;
        h8v wf2 = (g< 2) ? *(const h8v*)(PW + 256 + (g*16 + c)*4) : zero8;
        float bq0 = PW[384 + c];
        float bq1 = (c<8) ? PW[400 + c] : 0.f;
        float bao = (c<8) ? PW[408 + c] : 0.f;
        float bf1 = PW[416 + c];
        float bf2 = (c<8) ? PW[432 + c] : 0.f;
        float g1c = (c<8) ? PW[440 + c] : 0.f;
        float b1c = (c<8) ? PW[448 + c] : 0.f;
        float g2c = (c<8) ? PW[456 + c] : 0.f;
        float b2c = (c<8) ? PW[464 + c] : 0.f;

        // ---- Phase A: QKV GEMM + stage Q/K/V to LDS ----
        #pragma unroll
        for (int si = 0; si < 5; ++si) {
            h8v af = (g==0) ? *(const h8v*)&XA[(si*16 + c)*16] : zero8;
            f32x4 c0 = {bq0,bq0,bq0,bq0};
            f32x4 c1 = {bq1,bq1,bq1,bq1};
            c0 = MFMA16x16x32(af, wq0, c0, 0,0,0);
            c1 = MFMA16x16x32(af, wq1, c1, 0,0,0);
            #pragma unroll
            for (int rr = 0; rr < 4; ++rr) {
                int s = si*16 + g*4 + rr;
                if (c < 8) QA[s*8 + c]       = (__fp16)c0[rr];
                else       KB[s*8 + (c-8)]   = (__fp16)c0[rr];
            }
            if (c < 8) {
                u32x2 vp;
                vp.x = pkh(c1[0], c1[1]);
                vp.y = pkh(c1[2], c1[3]);
                *(u32x2*)&VT[c*80 + si*16 + g*4] = vp;
            }
        }

        // ---- Phase B: attention ----
        h8v qf[5], kbr[5], vb[5];
        #pragma unroll
        for (int tj = 0; tj < 5; ++tj) {
            qf[tj]  = (g==0) ? *(const h8v*)&QA[(tj*16 + c)*8] : zero8;
            kbr[tj] = (g==0) ? *(const h8v*)&KB[(tj*16 + c)*8] : zero8;
        }
        #pragma unroll
        for (int ch = 0; ch < 5; ++ch) {
            int tb = ch*32 + g*8;
            int hb = (tb >= 80) ? 1 : 0;
            int t0 = tb - hb*80;
            h8v v = zero8;
            if (c < 8) {
                if ((c >> 2) == hb) v = *(const h8v*)&VT[c*80 + t0];
            } else if (c == 8) {         // ones col -> rowsum head0
                if (!hb) v = ones8;
            } else if (c == 9) {         // ones col -> rowsum head1
                if (hb)  v = ones8;
            }
            vb[ch] = v;
        }

        #pragma unroll
        for (int si = 0; si < 5; ++si) {
            #pragma unroll
            for (int h = 0; h < 2; ++h) {
                #pragma unroll
                for (int tj = 0; tj < 5; ++tj) {
                    u32x4 kr = bcu4(kbr[tj]);
                    h8v kf = h ? bch8((u32x4){0u,0u,kr.z,kr.w})
                               : bch8((u32x4){kr.x,kr.y,0u,0u});
                    f32x4 sc = {0.f,0.f,0.f,0.f};
                    sc = MFMA16x16x32(qf[si], kf, sc, 0,0,0);
                    #pragma unroll
                    for (int rr = 0; rr < 4; ++rr) {
                        float e = __builtin_amdgcn_exp2f(sc[rr]);
                        if (tj == 4 && c >= 3) e = 0.f;   // mask t >= 67
                        PL[(g*4 + rr)*168 + h*80 + tj*16 + c] = (__fp16)e;
                    }
                }
            }
            // PV over (t,h) chunks; cols 8/9 accumulate per-head rowsums
            f32x4 o = {0.f,0.f,0.f,0.f};
            #pragma unroll
            for (int ch = 0; ch < 5; ++ch) {
                h8v pa = *(const h8v*)&PL[c*168 + ch*32 + g*8];
                o = MFMA16x16x32(pa, vb[ch], o, 0,0,0);
            }
            int src = (lid & 48) | (8 + (c >> 2));
            #pragma unroll
            for (int rr = 0; rr < 4; ++rr) {
                float rs = __shfl(o[rr], src, 64);
                o[rr] *= __builtin_amdgcn_rcpf(rs);
            }
            if (c < 8) {
                #pragma unroll
                for (int rr = 0; rr < 4; ++rr)
                    XA[(si*16 + g*4 + rr)*16 + c] = (__fp16)o[rr];
            }
        }

        // ---- Phase C: attn_out + residual + LN1 (write post-LN1 x to XA) ----
        #pragma unroll
        for (int si = 0; si < 5; ++si) {
            h8v oaf = (g==0) ? *(const h8v*)&XA[(si*16 + c)*16] : zero8;
            f32x4 a = {bao,bao,bao,bao};
            a = MFMA16x16x32(oaf, wao, a, 0,0,0);
            xc[si] += a;
        }
        #pragma unroll
        for (int si = 0; si < 5; ++si) {
            f32x4 X = xc[si];
            f32x4 sx = X, sq = X*X;
            #pragma unroll
            for (int m = 1; m <= 4; m <<= 1) {
                #pragma unroll
                for (int rr = 0; rr < 4; ++rr) {
                    sx[rr] += __shfl_xor(sx[rr], m, 64);
                    sq[rr] += __shfl_xor(sq[rr], m, 64);
                }
            }
            #pragma unroll
            for (int rr = 0; rr < 4; ++rr) {
                float mean = sx[rr] * 0.125f;
                float var  = sq[rr] * 0.125f - mean*mean;
                float rs   = __builtin_amdgcn_rsqf(var + 1e-5f);
                float y    = (X[rr] - mean) * rs * g1c + b1c;
                if (c < 8) X[rr] = y;          // keep zeros at c>=8
            }
            xc[si] = X;
            if (c < 8) {
                #pragma unroll
                for (int rr = 0; rr < 4; ++rr)
                    XA[(si*16 + g*4 + rr)*16 + c] = (__fp16)X[rr];
            }
        }

        // ---- Phase D: FF (t1 stored in XA cols 0..15), residual, LN2 ----
        #pragma unroll
        for (int si = 0; si < 5; ++si) {
            h8v xaf = (g==0) ? *(const h8v*)&XA[(si*16 + c)*16] : zero8;
            f32x4 t = {bf1,bf1,bf1,bf1};
            t = MFMA16x16x32(xaf, wf1, t, 0,0,0);
            #pragma unroll
            for (int rr = 0; rr < 4; ++rr)
                XA[(si*16 + g*4 + rr)*16 + c] = (__fp16)fmaxf(t[rr], 0.f);
        }
        #pragma unroll
        for (int si = 0; si < 5; ++si) {
            h8v tf = (g<2) ? *(const h8v*)&XA[(si*16 + c)*16 + g*8] : zero8;
            f32x4 a = {bf2,bf2,bf2,bf2};
            a = MFMA16x16x32(tf, wf2, a, 0,0,0);
            xc[si] += a;
        }
        #pragma unroll
        for (int si = 0; si < 5; ++si) {
            f32x4 X = xc[si];
            f32x4 sx = X, sq = X*X;
            #pragma unroll
            for (int m = 1; m <= 4; m <<= 1) {
                #pragma unroll
                for (int rr = 0; rr < 4; ++rr) {
                    sx[rr] += __shfl_xor(sx[rr], m, 64);
                    sq[rr] += __shfl_xor(sq[rr], m, 64);
                }
            }
            #pragma unroll
            for (int rr = 0; rr < 4; ++rr) {
                float mean = sx[rr] * 0.125f;
                float var  = sq[rr] * 0.125f - mean*mean;
                float rs   = __builtin_amdgcn_rsqf(var + 1e-5f);
                float y    = (X[rr] - mean) * rs * g2c + b2c;
                if (c < 8) X[rr] = y;
            }
            xc[si] = X;
            if (c < 8) {
                #pragma unroll
                for (int rr = 0; rr < 4; ++rr)
                    XA[(si*16 + g*4 + rr)*16 + c] = (__fp16)X[rr];   // next layer x
            }
        }
    }

    // ---- store xf[n][s][e] f32 ----
    #pragma unroll
    for (int si = 0; si < 5; ++si) {
        #pragma unroll
        for (int rr = 0; rr < 4; ++rr) {
            int s = si*16 + g*4 + rr;
            if (c < 8 && s < SEQ)
                xf[(size_t)n*KF + s*8 + c] = xc[si][rr];
        }
    }
}

// wt[k][c] = ow[c][k]
__global__ void tr_kernel(const float* __restrict__ ow, float* __restrict__ wt)
{
    int i = blockIdx.x * 256 + threadIdx.x;
    if (i < OUTC * KF) {
        int c = i / KF, k = i - c * KF;
        wt[k * OUTC + c] = ow[i];
    }
}

// out = tanh(Xf[32768,536] @ Wt[536,128] + b)
__global__ __launch_bounds__(256, 4)
void out_kernel(const float* __restrict__ xf, const float* __restrict__ wt,
                const float* __restrict__ ob, float* __restrict__ out)
{
    __shared__ float Xs[32][68];
    const int lid = threadIdx.x;
    const int tx  = lid & 31;
    const int ty  = lid >> 5;
    const int n0  = blockIdx.x * 32;

    float acc[4][4] = {};

    #pragma unroll 1
    for (int kc = 0; kc < 9; ++kc) {
        const int kb = kc * 64;
        const int kw = (kc < 8) ? 64 : 24;
        __syncthreads();
        const int nvec = 32 * (kw >> 2);
        for (int i = lid; i < nvec; i += 256) {
            int r = i / (kw >> 2), kq = i - r * (kw >> 2);
            *(float4*)&Xs[r][kq*4] =
                *(const float4*)&xf[(size_t)(n0 + r) * KF + kb + kq*4];
        }
        __syncthreads();
        #pragma unroll 4
        for (int k = 0; k < kw; ++k) {
            float4 w4 = *(const float4*)&wt[(size_t)(kb + k) * OUTC + tx*4];
            #pragma unroll
            for (int i = 0; i < 4; ++i) {
                float x = Xs[ty*4 + i][k];
                acc[i][0] += x*w4.x; acc[i][1] += x*w4.y;
                acc[i][2] += x*w4.z; acc[i][3] += x*w4.w;
            }
        }
    }

    const float4 bb = *(const float4*)&ob[tx*4];
    #pragma unroll
    for (int i = 0; i < 4; ++i) {
        int r = n0 + ty*4 + i;
        float4 v;
        v.x = tanhf(acc[i][0] + bb.x);
        v.y = tanhf(acc[i][1] + bb.y);
        v.z = tanhf(acc[i][2] + bb.z);
        v.w = tanhf(acc[i][3] + bb.w);
        *(float4*)(out + (size_t)r * OUTC + tx*4) = v;
    }
}

extern "C" void kernel_launch(void* const* d_in, const int* in_sizes, int n_in,
                              void* d_out, int out_size, void* d_ws, size_t ws_size,
                              hipStream_t stream) {
    (void)in_sizes; (void)n_in; (void)out_size; (void)ws_size;
    const float* pose = (const float*)d_in[0];
    const float* ew   = (const float*)d_in[1];
    const float* eb   = (const float*)d_in[2];
    const float* ipw  = (const float*)d_in[3];
    const float* ipb  = (const float*)d_in[4];
    const float* aow  = (const float*)d_in[5];
    const float* aob  = (const float*)d_in[6];
    const float* f1w  = (const float*)d_in[7];
    const float* f1b  = (const float*)d_in[8];
    const float* f2w  = (const float*)d_in[9];
    const float* f2b  = (const float*)d_in[10];
    const float* g1   = (const float*)d_in[11];
    const float* b1   = (const float*)d_in[12];
    const float* g2   = (const float*)d_in[13];
    const float* b2   = (const float*)d_in[14];
    const float* ow   = (const float*)d_in[15];
    const float* ob   = (const float*)d_in[16];

    float* xf  = (float*)d_ws;                  // 70.25 MB
    float* wt  = xf + (size_t)NTOT * KF;        // 268 KB
    // wpk aliases wt: pack+enc complete (stream-ordered) before tr_kernel
    // overwrites the region; 12*512 floats << KF*OUTC floats.
    float* wpk = wt;

    pack_kernel<<<L, 512, 0, stream>>>(ipw, ipb, aow, aob, f1w, f1b, f2w, f2b,
                                       g1, b1, g2, b2, wpk);
    enc_kernel<<<NTOT / 4, 256, 0, stream>>>(pose, ew, eb, wpk, xf);
    tr_kernel<<<(OUTC*KF + 255)/256, 256, 0, stream>>>(ow, wt);
    out_kernel<<<NTOT / 32, 256, 0, stream>>>(xf, wt, ob, (float*)d_out);
}

// Round 5
// 1814.614 us; speedup vs baseline: 1.4616x; 1.4616x over previous
//
#include <hip/hip_runtime.h>
#include <math.h>

// Problem constants
#define NTOT 32768   // T*B
#define CIN  201
#define S    67      // keypoints (seq len)
#define E    8
#define H    2
#define L    12
#define FF   16
#define OUTC 128
#define KF   536     // S*E
#define EPB  7       // elements per block
#define LPE  34      // lanes per element; lane j owns rows 2j, 2j+1 (row 67 = pad)
#define THREADS 256  // 7*34 = 238 active (93%)
#define NPAIR 34     // t-pair slots; slot 33 = {t=66 real, t=67 zero-pad}

typedef float v2f __attribute__((ext_vector_type(2)));

#if __has_builtin(__builtin_amdgcn_exp2f)
#define EXP2F(x) __builtin_amdgcn_exp2f(x)
#else
#define EXP2F(x) exp2f(x)
#endif
#if __has_builtin(__builtin_amdgcn_rcpf)
#define RCPF(x) __builtin_amdgcn_rcpf(x)
#else
#define RCPF(x) (1.0f/(x))
#endif
#if __has_builtin(__builtin_amdgcn_rsqf)
#define RSQF(x) __builtin_amdgcn_rsqf(x)
#else
#define RSQF(x) rsqrtf(x)
#endif

// 0.5 (=1/sqrt(DH)) * log2(e)
#define QSCALE 0.7213475204444817f

__device__ __forceinline__ v2f sp(float x) { return (v2f){x, x}; }

__device__ __forceinline__ void ln8p(v2f* x, const float* __restrict__ gg,
                                     const float* __restrict__ bb) {
    v2f m = {0.f, 0.f};
    #pragma unroll
    for (int e = 0; e < E; ++e) m += x[e];
    m *= 0.125f;
    v2f v = {0.f, 0.f};
    #pragma unroll
    for (int e = 0; e < E; ++e) { v2f d = x[e] - m; v += d * d; }
    v *= 0.125f;
    v2f rs;
    rs.x = RSQF(v.x + 1e-5f);
    rs.y = RSQF(v.y + 1e-5f);
    #pragma unroll
    for (int e = 0; e < E; ++e) x[e] = (x[e] - m) * rs * sp(gg[e]) + sp(bb[e]);
}

// Head-multiplexed K/V LDS: one head resident at a time.
// 4 * 7 * 34 * 16 B = 15232 B -> 10 blocks by LDS, 8 by thread cap
// -> 32 waves/CU (100% occupancy) vs r0's 5 blocks (50%).
__global__ __launch_bounds__(THREADS, 8)
void enc_kernel(const float* __restrict__ pose,
                const float* __restrict__ ew,  const float* __restrict__ ebias,
                const float* __restrict__ ipw, const float* __restrict__ ipb,
                const float* __restrict__ aow, const float* __restrict__ aob,
                const float* __restrict__ f1w, const float* __restrict__ f1b,
                const float* __restrict__ f2w, const float* __restrict__ f2b,
                const float* __restrict__ g1,  const float* __restrict__ b1,
                const float* __restrict__ g2,  const float* __restrict__ b2,
                float* __restrict__ xf)
{
    // t-pair interleaved K/V for the CURRENT head; slot i holds t-pair {2i,2i+1}.
    // KA={kx_t0,kx_t1,ky_t0,ky_t1}, KB={kz..,kw..}; VA/VB same for v.
    __shared__ float4 KA[EPB][NPAIR];
    __shared__ float4 KB[EPB][NPAIR];
    __shared__ float4 VA[EPB][NPAIR];
    __shared__ float4 VB[EPB][NPAIR];

    const int lid = threadIdx.x;
    const int g   = lid / LPE;          // element in block (0..6 valid)
    const int j   = lid - g * LPE;      // pair index (0..33)
    const int n   = blockIdx.x * EPB + g;
    const bool active = (g < EPB) && (n < NTOT);
    const bool pad = (j == LPE - 1);    // lane 33: r1 = row 67 (doesn't exist)
    const int r0 = 2 * j;

    // ---- embed (rows r0=2j, r1=2j+1 packed into halves) ----
    v2f xr[E];
    if (active) {
        const float* p0 = pose + (size_t)n * CIN + 3 * r0;
        const float* p1 = pad ? p0 : (p0 + 3);
        v2f c0 = {p0[0], p1[0]};
        v2f c1 = {p0[1], p1[1]};
        v2f c2 = {p0[2], p1[2]};
        #pragma unroll
        for (int e = 0; e < E; ++e)
            xr[e] = sp(ebias[e]) + c0 * sp(ew[e*3+0]) + c1 * sp(ew[e*3+1])
                                 + c2 * sp(ew[e*3+2]);
    }

    #pragma unroll 1
    for (int l = 0; l < L; ++l) {
        const float* W  = ipw + l * 192;   // [24][8] row-major, wave-uniform
        const float* Bq = ipb + l * 24;

        v2f os[E];   // os[e] = {o[r0][e], o[r1][e]}, filled 4 per head

        #pragma unroll
        for (int h = 0; h < H; ++h) {
            // ---- per-head QKV: rows Q=4h..4h+3, K=8+4h.., V=16+4h.. ----
            v2f qp[4];       // scaled q for this head
            v2f kvp[8];      // k (0..3), v (4..7) for this head
            if (active) {
                #pragma unroll
                for (int c = 0; c < 12; ++c) {
                    const int jo = 4*h + c + ((c >> 2) << 2);  // Q/K/V row
                    v2f a = sp(Bq[jo]);
                    #pragma unroll
                    for (int e = 0; e < E; ++e) a += xr[e] * sp(W[jo*8 + e]);
                    if (c < 4) qp[c] = a * QSCALE;
                    else       kvp[c-4] = a;
                }
                if (pad) {   // row 67: k=0 (exp2(0)=1, fixed by lsum-1), v=0
                    #pragma unroll
                    for (int c = 0; c < 8; ++c) kvp[c].y = 0.f;
                }
            }
            __syncthreads();   // previous phase's readers done
            if (active) {
                KA[g][j] = make_float4(kvp[0].x, kvp[0].y, kvp[1].x, kvp[1].y);
                KB[g][j] = make_float4(kvp[2].x, kvp[2].y, kvp[3].x, kvp[3].y);
                VA[g][j] = make_float4(kvp[4].x, kvp[4].y, kvp[5].x, kvp[5].y);
                VB[g][j] = make_float4(kvp[6].x, kvp[6].y, kvp[7].x, kvp[7].y);
            }
            __syncthreads();   // K/V of this head visible

            if (active) {
                const float4* pKA = KA[g];
                const float4* pKB = KB[g];
                const float4* pVA = VA[g];
                const float4* pVB = VB[g];
                // row-specific q splats (low/high halves of qp)
                const v2f q0l = sp(qp[0].x), q0h = sp(qp[0].y);
                const v2f q1l = sp(qp[1].x), q1h = sp(qp[1].y);
                const v2f q2l = sp(qp[2].x), q2h = sp(qp[2].y);
                const v2f q3l = sp(qp[3].x), q3h = sp(qp[3].y);
                v2f ls0 = {0.f,0.f}, ls1 = {0.f,0.f};
                v2f oc00={0.f,0.f}, oc01={0.f,0.f}, oc02={0.f,0.f}, oc03={0.f,0.f};
                v2f oc10={0.f,0.f}, oc11={0.f,0.f}, oc12={0.f,0.f}, oc13={0.f,0.f};
                #pragma unroll
                for (int i = 0; i < NPAIR; ++i) {     // t = 0..67 (67 = zero-pad)
                    float4 ka = pKA[i], kb = pKB[i];
                    float4 va = pVA[i], vb = pVB[i];
                    v2f kx = *(const v2f*)&ka.x, ky = *(const v2f*)&ka.z;
                    v2f kz = *(const v2f*)&kb.x, kw = *(const v2f*)&kb.z;
                    v2f sc0 = q0l*kx + q1l*ky + q2l*kz + q3l*kw;   // row r0, {t0,t1}
                    v2f sc1 = q0h*kx + q1h*ky + q2h*kz + q3h*kw;   // row r1
                    v2f e0, e1;
                    e0.x = EXP2F(sc0.x);  e0.y = EXP2F(sc0.y);
                    e1.x = EXP2F(sc1.x);  e1.y = EXP2F(sc1.y);
                    ls0 += e0;  ls1 += e1;
                    v2f v0 = *(const v2f*)&va.x, v1 = *(const v2f*)&va.z;
                    v2f v2 = *(const v2f*)&vb.x, v3 = *(const v2f*)&vb.z;
                    oc00 += e0*v0; oc01 += e0*v1; oc02 += e0*v2; oc03 += e0*v3;
                    oc10 += e1*v0; oc11 += e1*v1; oc12 += e1*v2; oc13 += e1*v3;
                }
                float l0 = ls0.x + ls0.y - 1.0f;   // remove pad's exp2(0)=1
                float l1 = ls1.x + ls1.y - 1.0f;
                float i0 = RCPF(l0), i1 = RCPF(l1);
                os[4*h+0] = (v2f){(oc00.x+oc00.y)*i0, (oc10.x+oc10.y)*i1};
                os[4*h+1] = (v2f){(oc01.x+oc01.y)*i0, (oc11.x+oc11.y)*i1};
                os[4*h+2] = (v2f){(oc02.x+oc02.y)*i0, (oc12.x+oc12.y)*i1};
                os[4*h+3] = (v2f){(oc03.x+oc03.y)*i0, (oc13.x+oc13.y)*i1};
            }
        }

        if (active) {
            // attn_out + residual + LN1
            {
                const float* WA = aow + l*64;   // [8][8]
                const float* BA = aob + l*8;
                #pragma unroll
                for (int e = 0; e < E; ++e) {
                    v2f a = sp(BA[e]);
                    #pragma unroll
                    for (int e2 = 0; e2 < E; ++e2) a += os[e2] * sp(WA[e*8 + e2]);
                    xr[e] += a;
                }
            }
            ln8p(xr, g1 + l*E, b1 + l*E);

            // FF
            {
                const float* W1 = f1w + l*128;  // [16][8]
                const float* B1 = f1b + l*16;
                const float* W2 = f2w + l*128;  // [8][16]
                const float* B2 = f2b + l*8;
                v2f t1[FF];
                #pragma unroll
                for (int f = 0; f < FF; ++f) {
                    v2f a = sp(B1[f]);
                    #pragma unroll
                    for (int e = 0; e < E; ++e) a += xr[e] * sp(W1[f*8 + e]);
                    a.x = fmaxf(a.x, 0.f);
                    a.y = fmaxf(a.y, 0.f);
                    t1[f] = a;
                }
                #pragma unroll
                for (int e = 0; e < E; ++e) {
                    v2f a = sp(B2[e]);
                    #pragma unroll
                    for (int f = 0; f < FF; ++f) a += t1[f] * sp(W2[e*16 + f]);
                    xr[e] += a;
                }
            }
            ln8p(xr, g2 + l*E, b2 + l*E);
        }
        // no trailing barrier: next layer's write is preceded by its own barrier
    }

    if (active) {
        float* dst = xf + (size_t)n * KF + r0 * E;   // rows 2j,2j+1 contiguous
        *(float4*)(dst + 0) = make_float4(xr[0].x, xr[1].x, xr[2].x, xr[3].x);
        *(float4*)(dst + 4) = make_float4(xr[4].x, xr[5].x, xr[6].x, xr[7].x);
        if (!pad) {
            *(float4*)(dst + 8)  = make_float4(xr[0].y, xr[1].y, xr[2].y, xr[3].y);
            *(float4*)(dst + 12) = make_float4(xr[4].y, xr[5].y, xr[6].y, xr[7].y);
        }
    }
}

// wt[k][c] = ow[c][k]
__global__ void tr_kernel(const float* __restrict__ ow, float* __restrict__ wt)
{
    int i = blockIdx.x * 256 + threadIdx.x;
    if (i < OUTC * KF) {
        int c = i / KF, k = i - c * KF;
        wt[k * OUTC + c] = ow[i];
    }
}

// out = tanh(Xf[32768,536] @ Wt[536,128] + b)
__global__ __launch_bounds__(256, 4)
void out_kernel(const float* __restrict__ xf, const float* __restrict__ wt,
                const float* __restrict__ ob, float* __restrict__ out)
{
    __shared__ float Xs[32][68];
    const int lid = threadIdx.x;
    const int tx  = lid & 31;
    const int ty  = lid >> 5;
    const int n0  = blockIdx.x * 32;

    float acc[4][4] = {};

    #pragma unroll 1
    for (int kc = 0; kc < 9; ++kc) {
        const int kb = kc * 64;
        const int kw = (kc < 8) ? 64 : 24;
        __syncthreads();
        const int nvec = 32 * (kw >> 2);
        for (int i = lid; i < nvec; i += 256) {
            int r = i / (kw >> 2), kq = i - r * (kw >> 2);
            *(float4*)&Xs[r][kq*4] =
                *(const float4*)&xf[(size_t)(n0 + r) * KF + kb + kq*4];
        }
        __syncthreads();
        #pragma unroll 4
        for (int k = 0; k < kw; ++k) {
            float4 w4 = *(const float4*)&wt[(size_t)(kb + k) * OUTC + tx*4];
            #pragma unroll
            for (int i = 0; i < 4; ++i) {
                float x = Xs[ty*4 + i][k];
                acc[i][0] += x*w4.x; acc[i][1] += x*w4.y;
                acc[i][2] += x*w4.z; acc[i][3] += x*w4.w;
            }
        }
    }

    const float4 bb = *(const float4*)&ob[tx*4];
    #pragma unroll
    for (int i = 0; i < 4; ++i) {
        int r = n0 + ty*4 + i;
        float4 v;
        v.x = tanhf(acc[i][0] + bb.x);
        v.y = tanhf(acc[i][1] + bb.y);
        v.z = tanhf(acc[i][2] + bb.z);
        v.w = tanhf(acc[i][3] + bb.w);
        *(float4*)(out + (size_t)r * OUTC + tx*4) = v;
    }
}

extern "C" void kernel_launch(void* const* d_in, const int* in_sizes, int n_in,
                              void* d_out, int out_size, void* d_ws, size_t ws_size,
                              hipStream_t stream) {
    (void)in_sizes; (void)n_in; (void)out_size; (void)ws_size;
    const float* pose = (const float*)d_in[0];
    const float* ew   = (const float*)d_in[1];
    const float* eb   = (const float*)d_in[2];
    const float* ipw  = (const float*)d_in[3];
    const float* ipb  = (const float*)d_in[4];
    const float* aow  = (const float*)d_in[5];
    const float* aob  = (const float*)d_in[6];
    const float* f1w  = (const float*)d_in[7];
    const float* f1b  = (const float*)d_in[8];
    const float* f2w  = (const float*)d_in[9];
    const float* f2b  = (const float*)d_in[10];
    const float* g1   = (const float*)d_in[11];
    const float* b1   = (const float*)d_in[12];
    const float* g2   = (const float*)d_in[13];
    const float* b2   = (const float*)d_in[14];
    const float* ow   = (const float*)d_in[15];
    const float* ob   = (const float*)d_in[16];

    float* xf = (float*)d_ws;                               // 70.25 MB
    float* wt = xf + (size_t)NTOT * KF;                     // 268 KB

    const int grid1 = (NTOT + EPB - 1) / EPB;               // 4682
    enc_kernel<<<grid1, THREADS, 0, stream>>>(pose, ew, eb, ipw, ipb, aow, aob,
                                              f1w, f1b, f2w, f2b, g1, b1, g2, b2, xf);
    tr_kernel<<<(OUTC*KF + 255)/256, 256, 0, stream>>>(ow, wt);
    out_kernel<<<NTOT / 32, 256, 0, stream>>>(xf, wt, ob, (float*)d_out);
}

// Round 6
// 1663.800 us; speedup vs baseline: 1.5941x; 1.0906x over previous
//
#include <hip/hip_runtime.h>
#include <math.h>

// Problem constants
#define NTOT 32768   // T*B
#define CIN  201
#define S    67      // keypoints (seq len)
#define E    8
#define H    2
#define L    12
#define FF   16
#define OUTC 128
#define KF   536     // S*E
#define EPB  7       // elements per block
#define LPE  34      // lanes per element; lane j owns rows 2j, 2j+1 (row 67 = pad)
#define THREADS 256  // 7*34 = 238 active (93%)
#define NPAIR 34     // t-pair slots; slot 33 = {t=66 real, t=67 zero-pad}

typedef float v2f __attribute__((ext_vector_type(2)));

#if __has_builtin(__builtin_amdgcn_exp2f)
#define EXP2F(x) __builtin_amdgcn_exp2f(x)
#else
#define EXP2F(x) exp2f(x)
#endif
#if __has_builtin(__builtin_amdgcn_rcpf)
#define RCPF(x) __builtin_amdgcn_rcpf(x)
#else
#define RCPF(x) (1.0f/(x))
#endif
#if __has_builtin(__builtin_amdgcn_rsqf)
#define RSQF(x) __builtin_amdgcn_rsqf(x)
#else
#define RSQF(x) rsqrtf(x)
#endif

// 0.5 (=1/sqrt(DH)) * log2(e)
#define QSCALE 0.7213475204444817f

__device__ __forceinline__ v2f sp(float x) { return (v2f){x, x}; }

__device__ __forceinline__ void ln8p(v2f* x, const float* __restrict__ gg,
                                     const float* __restrict__ bb) {
    v2f m = {0.f, 0.f};
    #pragma unroll
    for (int e = 0; e < E; ++e) m += x[e];
    m *= 0.125f;
    v2f v = {0.f, 0.f};
    #pragma unroll
    for (int e = 0; e < E; ++e) { v2f d = x[e] - m; v += d * d; }
    v *= 0.125f;
    v2f rs;
    rs.x = RSQF(v.x + 1e-5f);
    rs.y = RSQF(v.y + 1e-5f);
    #pragma unroll
    for (int e = 0; e < E; ++e) x[e] = (x[e] - m) * rs * sp(gg[e]) + sp(bb[e]);
}

// Head-multiplexed K/V LDS: one head resident at a time.
// 4 * 7 * 34 * 16 B = 15232 B -> 10 blocks by LDS, 8 by thread cap.
// __launch_bounds__(256, 6): VGPR cap 85/wave (no spill for this fp32 body;
// (256,8)'s 64-cap caused 6.3 GB of scratch traffic in round 5).
__global__ __launch_bounds__(THREADS, 6)
void enc_kernel(const float* __restrict__ pose,
                const float* __restrict__ ew,  const float* __restrict__ ebias,
                const float* __restrict__ ipw, const float* __restrict__ ipb,
                const float* __restrict__ aow, const float* __restrict__ aob,
                const float* __restrict__ f1w, const float* __restrict__ f1b,
                const float* __restrict__ f2w, const float* __restrict__ f2b,
                const float* __restrict__ g1,  const float* __restrict__ b1,
                const float* __restrict__ g2,  const float* __restrict__ b2,
                float* __restrict__ xf)
{
    // t-pair interleaved K/V for the CURRENT head; slot i holds t-pair {2i,2i+1}.
    // KA={kx_t0,kx_t1,ky_t0,ky_t1}, KB={kz..,kw..}; VA/VB same for v.
    __shared__ float4 KA[EPB][NPAIR];
    __shared__ float4 KB[EPB][NPAIR];
    __shared__ float4 VA[EPB][NPAIR];
    __shared__ float4 VB[EPB][NPAIR];

    const int lid = threadIdx.x;
    const int g   = lid / LPE;          // element in block (0..6 valid)
    const int j   = lid - g * LPE;      // pair index (0..33)
    const int n   = blockIdx.x * EPB + g;
    const bool active = (g < EPB) && (n < NTOT);
    const bool pad = (j == LPE - 1);    // lane 33: r1 = row 67 (doesn't exist)
    const int r0 = 2 * j;

    // ---- embed (rows r0=2j, r1=2j+1 packed into halves) ----
    v2f xr[E];
    if (active) {
        const float* p0 = pose + (size_t)n * CIN + 3 * r0;
        const float* p1 = pad ? p0 : (p0 + 3);
        v2f c0 = {p0[0], p1[0]};
        v2f c1 = {p0[1], p1[1]};
        v2f c2 = {p0[2], p1[2]};
        #pragma unroll
        for (int e = 0; e < E; ++e)
            xr[e] = sp(ebias[e]) + c0 * sp(ew[e*3+0]) + c1 * sp(ew[e*3+1])
                                 + c2 * sp(ew[e*3+2]);
    }

    #pragma unroll 1
    for (int l = 0; l < L; ++l) {
        const float* W  = ipw + l * 192;   // [24][8] row-major, wave-uniform
        const float* Bq = ipb + l * 24;

        v2f os[E];   // os[e] = {o[r0][e], o[r1][e]}, filled 4 per head

        #pragma unroll
        for (int h = 0; h < H; ++h) {
            // ---- per-head QKV: rows Q=4h..4h+3, K=8+4h.., V=16+4h.. ----
            v2f qp[4];       // scaled q for this head
            v2f kvp[8];      // k (0..3), v (4..7) for this head
            if (active) {
                #pragma unroll
                for (int c = 0; c < 12; ++c) {
                    const int jo = 4*h + c + ((c >> 2) << 2);  // Q/K/V row
                    v2f a = sp(Bq[jo]);
                    #pragma unroll
                    for (int e = 0; e < E; ++e) a += xr[e] * sp(W[jo*8 + e]);
                    if (c < 4) qp[c] = a * QSCALE;
                    else       kvp[c-4] = a;
                }
                if (pad) {   // row 67: k=0 (exp2(0)=1, fixed by lsum-1), v=0
                    #pragma unroll
                    for (int c = 0; c < 8; ++c) kvp[c].y = 0.f;
                }
            }
            __syncthreads();   // previous phase's readers done
            if (active) {
                KA[g][j] = make_float4(kvp[0].x, kvp[0].y, kvp[1].x, kvp[1].y);
                KB[g][j] = make_float4(kvp[2].x, kvp[2].y, kvp[3].x, kvp[3].y);
                VA[g][j] = make_float4(kvp[4].x, kvp[4].y, kvp[5].x, kvp[5].y);
                VB[g][j] = make_float4(kvp[6].x, kvp[6].y, kvp[7].x, kvp[7].y);
            }
            __syncthreads();   // K/V of this head visible

            if (active) {
                const float4* pKA = KA[g];
                const float4* pKB = KB[g];
                const float4* pVA = VA[g];
                const float4* pVB = VB[g];
                // row-specific q splats (low/high halves of qp)
                const v2f q0l = sp(qp[0].x), q0h = sp(qp[0].y);
                const v2f q1l = sp(qp[1].x), q1h = sp(qp[1].y);
                const v2f q2l = sp(qp[2].x), q2h = sp(qp[2].y);
                const v2f q3l = sp(qp[3].x), q3h = sp(qp[3].y);
                v2f ls0 = {0.f,0.f}, ls1 = {0.f,0.f};
                v2f oc00={0.f,0.f}, oc01={0.f,0.f}, oc02={0.f,0.f}, oc03={0.f,0.f};
                v2f oc10={0.f,0.f}, oc11={0.f,0.f}, oc12={0.f,0.f}, oc13={0.f,0.f};
                #pragma unroll
                for (int i = 0; i < NPAIR; ++i) {     // t = 0..67 (67 = zero-pad)
                    float4 ka = pKA[i], kb = pKB[i];
                    float4 va = pVA[i], vb = pVB[i];
                    v2f kx = *(const v2f*)&ka.x, ky = *(const v2f*)&ka.z;
                    v2f kz = *(const v2f*)&kb.x, kw = *(const v2f*)&kb.z;
                    v2f sc0 = q0l*kx + q1l*ky + q2l*kz + q3l*kw;   // row r0, {t0,t1}
                    v2f sc1 = q0h*kx + q1h*ky + q2h*kz + q3h*kw;   // row r1
                    v2f e0, e1;
                    e0.x = EXP2F(sc0.x);  e0.y = EXP2F(sc0.y);
                    e1.x = EXP2F(sc1.x);  e1.y = EXP2F(sc1.y);
                    ls0 += e0;  ls1 += e1;
                    v2f v0 = *(const v2f*)&va.x, v1 = *(const v2f*)&va.z;
                    v2f v2 = *(const v2f*)&vb.x, v3 = *(const v2f*)&vb.z;
                    oc00 += e0*v0; oc01 += e0*v1; oc02 += e0*v2; oc03 += e0*v3;
                    oc10 += e1*v0; oc11 += e1*v1; oc12 += e1*v2; oc13 += e1*v3;
                }
                float l0 = ls0.x + ls0.y - 1.0f;   // remove pad's exp2(0)=1
                float l1 = ls1.x + ls1.y - 1.0f;
                float i0 = RCPF(l0), i1 = RCPF(l1);
                os[4*h+0] = (v2f){(oc00.x+oc00.y)*i0, (oc10.x+oc10.y)*i1};
                os[4*h+1] = (v2f){(oc01.x+oc01.y)*i0, (oc11.x+oc11.y)*i1};
                os[4*h+2] = (v2f){(oc02.x+oc02.y)*i0, (oc12.x+oc12.y)*i1};
                os[4*h+3] = (v2f){(oc03.x+oc03.y)*i0, (oc13.x+oc13.y)*i1};
            }
        }

        if (active) {
            // attn_out + residual + LN1
            {
                const float* WA = aow + l*64;   // [8][8]
                const float* BA = aob + l*8;
                #pragma unroll
                for (int e = 0; e < E; ++e) {
                    v2f a = sp(BA[e]);
                    #pragma unroll
                    for (int e2 = 0; e2 < E; ++e2) a += os[e2] * sp(WA[e*8 + e2]);
                    xr[e] += a;
                }
            }
            ln8p(xr, g1 + l*E, b1 + l*E);

            // FF
            {
                const float* W1 = f1w + l*128;  // [16][8]
                const float* B1 = f1b + l*16;
                const float* W2 = f2w + l*128;  // [8][16]
                const float* B2 = f2b + l*8;
                v2f t1[FF];
                #pragma unroll
                for (int f = 0; f < FF; ++f) {
                    v2f a = sp(B1[f]);
                    #pragma unroll
                    for (int e = 0; e < E; ++e) a += xr[e] * sp(W1[f*8 + e]);
                    a.x = fmaxf(a.x, 0.f);
                    a.y = fmaxf(a.y, 0.f);
                    t1[f] = a;
                }
                #pragma unroll
                for (int e = 0; e < E; ++e) {
                    v2f a = sp(B2[e]);
                    #pragma unroll
                    for (int f = 0; f < FF; ++f) a += t1[f] * sp(W2[e*16 + f]);
                    xr[e] += a;
                }
            }
            ln8p(xr, g2 + l*E, b2 + l*E);
        }
        // no trailing barrier: next layer's write is preceded by its own barrier
    }

    if (active) {
        float* dst = xf + (size_t)n * KF + r0 * E;   // rows 2j,2j+1 contiguous
        *(float4*)(dst + 0) = make_float4(xr[0].x, xr[1].x, xr[2].x, xr[3].x);
        *(float4*)(dst + 4) = make_float4(xr[4].x, xr[5].x, xr[6].x, xr[7].x);
        if (!pad) {
            *(float4*)(dst + 8)  = make_float4(xr[0].y, xr[1].y, xr[2].y, xr[3].y);
            *(float4*)(dst + 12) = make_float4(xr[4].y, xr[5].y, xr[6].y, xr[7].y);
        }
    }
}

// wt[k][c] = ow[c][k]
__global__ void tr_kernel(const float* __restrict__ ow, float* __restrict__ wt)
{
    int i = blockIdx.x * 256 + threadIdx.x;
    if (i < OUTC * KF) {
        int c = i / KF, k = i - c * KF;
        wt[k * OUTC + c] = ow[i];
    }
}

// out = tanh(Xf[32768,536] @ Wt[536,128] + b)
__global__ __launch_bounds__(256, 4)
void out_kernel(const float* __restrict__ xf, const float* __restrict__ wt,
                const float* __restrict__ ob, float* __restrict__ out)
{
    __shared__ float Xs[32][68];
    const int lid = threadIdx.x;
    const int tx  = lid & 31;
    const int ty  = lid >> 5;
    const int n0  = blockIdx.x * 32;

    float acc[4][4] = {};

    #pragma unroll 1
    for (int kc = 0; kc < 9; ++kc) {
        const int kb = kc * 64;
        const int kw = (kc < 8) ? 64 : 24;
        __syncthreads();
        const int nvec = 32 * (kw >> 2);
        for (int i = lid; i < nvec; i += 256) {
            int r = i / (kw >> 2), kq = i - r * (kw >> 2);
            *(float4*)&Xs[r][kq*4] =
                *(const float4*)&xf[(size_t)(n0 + r) * KF + kb + kq*4];
        }
        __syncthreads();
        #pragma unroll 4
        for (int k = 0; k < kw; ++k) {
            float4 w4 = *(const float4*)&wt[(size_t)(kb + k) * OUTC + tx*4];
            #pragma unroll
            for (int i = 0; i < 4; ++i) {
                float x = Xs[ty*4 + i][k];
                acc[i][0] += x*w4.x; acc[i][1] += x*w4.y;
                acc[i][2] += x*w4.z; acc[i][3] += x*w4.w;
            }
        }
    }

    const float4 bb = *(const float4*)&ob[tx*4];
    #pragma unroll
    for (int i = 0; i < 4; ++i) {
        int r = n0 + ty*4 + i;
        float4 v;
        v.x = tanhf(acc[i][0] + bb.x);
        v.y = tanhf(acc[i][1] + bb.y);
        v.z = tanhf(acc[i][2] + bb.z);
        v.w = tanhf(acc[i][3] + bb.w);
        *(float4*)(out + (size_t)r * OUTC + tx*4) = v;
    }
}

extern "C" void kernel_launch(void* const* d_in, const int* in_sizes, int n_in,
                              void* d_out, int out_size, void* d_ws, size_t ws_size,
                              hipStream_t stream) {
    (void)in_sizes; (void)n_in; (void)out_size; (void)ws_size;
    const float* pose = (const float*)d_in[0];
    const float* ew   = (const float*)d_in[1];
    const float* eb   = (const float*)d_in[2];
    const float* ipw  = (const float*)d_in[3];
    const float* ipb  = (const float*)d_in[4];
    const float* aow  = (const float*)d_in[5];
    const float* aob  = (const float*)d_in[6];
    const float* f1w  = (const float*)d_in[7];
    const float* f1b  = (const float*)d_in[8];
    const float* f2w  = (const float*)d_in[9];
    const float* f2b  = (const float*)d_in[10];
    const float* g1   = (const float*)d_in[11];
    const float* b1   = (const float*)d_in[12];
    const float* g2   = (const float*)d_in[13];
    const float* b2   = (const float*)d_in[14];
    const float* ow   = (const float*)d_in[15];
    const float* ob   = (const float*)d_in[16];

    float* xf = (float*)d_ws;                               // 70.25 MB
    float* wt = xf + (size_t)NTOT * KF;                     // 268 KB

    const int grid1 = (NTOT + EPB - 1) / EPB;               // 4682
    enc_kernel<<<grid1, THREADS, 0, stream>>>(pose, ew, eb, ipw, ipb, aow, aob,
                                              f1w, f1b, f2w, f2b, g1, b1, g2, b2, xf);
    tr_kernel<<<(OUTC*KF + 255)/256, 256, 0, stream>>>(ow, wt);
    out_kernel<<<NTOT / 32, 256, 0, stream>>>(xf, wt, ob, (float*)d_out);
}

// Round 7
// 1568.316 us; speedup vs baseline: 1.6912x; 1.0609x over previous
//
#include <hip/hip_runtime.h>
#include <math.h>

// Problem constants
#define NTOT 32768   // T*B
#define CIN  201
#define S    67      // keypoints (seq len)
#define E    8
#define H    2
#define L    12
#define FF   16
#define OUTC 128
#define KF   536     // S*E
#define EPB  7       // elements per block
#define LPE  34      // lanes per element; lane j owns rows 2j, 2j+1 (row 67 = pad)
#define THREADS 256  // 7*34 = 238 active (93%)
#define NPAIR 34     // t-pair slots; slot 33 = {t=66 real, t=67 zero-pad}

typedef float v2f __attribute__((ext_vector_type(2)));
typedef __fp16 h2  __attribute__((ext_vector_type(2)));

#if __has_builtin(__builtin_amdgcn_exp2f)
#define EXP2F(x) __builtin_amdgcn_exp2f(x)
#else
#define EXP2F(x) exp2f(x)
#endif
#if __has_builtin(__builtin_amdgcn_rcpf)
#define RCPF(x) __builtin_amdgcn_rcpf(x)
#else
#define RCPF(x) (1.0f/(x))
#endif
#if __has_builtin(__builtin_amdgcn_rsqf)
#define RSQF(x) __builtin_amdgcn_rsqf(x)
#else
#define RSQF(x) rsqrtf(x)
#endif

// f32 pair -> packed f16 pair (one v_cvt_pkrtz_f16_f32)
#if __has_builtin(__builtin_amdgcn_cvt_pkrtz)
__device__ __forceinline__ h2 cvh(float a, float b) {
    return __builtin_amdgcn_cvt_pkrtz(a, b);
}
#else
__device__ __forceinline__ h2 cvh(float a, float b) {
    h2 r; r.x = (__fp16)a; r.y = (__fp16)b; return r;
}
#endif
__device__ __forceinline__ float pkf(float a, float b) {
    return __builtin_bit_cast(float, cvh(a, b));
}
__device__ __forceinline__ h2 bch(float f) { return __builtin_bit_cast(h2, f); }

// fp32 += dot2(f16 pair, f16 pair): v_dot2_f32_f16, 2 MACs/instr
#if __has_builtin(__builtin_amdgcn_fdot2)
#define FDOT2(a, b, c) __builtin_amdgcn_fdot2((a), (b), (c), false)
#else
#define FDOT2(a, b, c) ((float)(a).x*(float)(b).x + (float)(a).y*(float)(b).y + (c))
#endif

// 0.5 (=1/sqrt(DH)) * log2(e)
#define QSCALE 0.7213475204444817f

__device__ __forceinline__ v2f sp(float x) { return (v2f){x, x}; }

__device__ __forceinline__ void ln8p(v2f* x, const float* __restrict__ gg,
                                     const float* __restrict__ bb) {
    v2f m = {0.f, 0.f};
    #pragma unroll
    for (int e = 0; e < E; ++e) m += x[e];
    m *= 0.125f;
    v2f v = {0.f, 0.f};
    #pragma unroll
    for (int e = 0; e < E; ++e) { v2f d = x[e] - m; v += d * d; }
    v *= 0.125f;
    v2f rs;
    rs.x = RSQF(v.x + 1e-5f);
    rs.y = RSQF(v.y + 1e-5f);
    #pragma unroll
    for (int e = 0; e < E; ++e) x[e] = (x[e] - m) * rs * sp(gg[e]) + sp(bb[e]);
}

// r0 structure; only V is stored f16-packed (K stays f32 -> scores exact).
// LDS: KA+KB (2*7616) + Vh (7616) = 22848 B -> 7 blocks/CU (vs r0's 5).
__global__ __launch_bounds__(THREADS, 7)
void enc_kernel(const float* __restrict__ pose,
                const float* __restrict__ ew,  const float* __restrict__ ebias,
                const float* __restrict__ ipw, const float* __restrict__ ipb,
                const float* __restrict__ aow, const float* __restrict__ aob,
                const float* __restrict__ f1w, const float* __restrict__ f1b,
                const float* __restrict__ f2w, const float* __restrict__ f2b,
                const float* __restrict__ g1,  const float* __restrict__ b1,
                const float* __restrict__ g2,  const float* __restrict__ b2,
                float* __restrict__ xf)
{
    // t-pair interleaved; slot i holds t-pair {2i, 2i+1}.
    // KA={kx_t0,kx_t1,ky_t0,ky_t1}, KB={kz..,kw..} (f32)
    // Vh[gh][i] = {v0_{t0,t1}, v1_{t0,t1}, v2_{t0,t1}, v3_{t0,t1}} (packed h2)
    __shared__ float4 KA[EPB * H][NPAIR];
    __shared__ float4 KB[EPB * H][NPAIR];
    __shared__ float4 Vh[EPB * H][NPAIR];

    const int lid = threadIdx.x;
    const int g   = lid / LPE;          // element in block (0..6 valid)
    const int j   = lid - g * LPE;      // pair index (0..33)
    const int n   = blockIdx.x * EPB + g;
    const bool active = (g < EPB) && (n < NTOT);
    const bool pad = (j == LPE - 1);    // lane 33: r1 = row 67 (doesn't exist)
    const int r0 = 2 * j;

    // ---- embed (rows r0=2j, r1=2j+1 packed into halves) ----
    v2f xr[E];
    if (active) {
        const float* p0 = pose + (size_t)n * CIN + 3 * r0;
        const float* p1 = pad ? p0 : (p0 + 3);
        v2f c0 = {p0[0], p1[0]};
        v2f c1 = {p0[1], p1[1]};
        v2f c2 = {p0[2], p1[2]};
        #pragma unroll
        for (int e = 0; e < E; ++e)
            xr[e] = sp(ebias[e]) + c0 * sp(ew[e*3+0]) + c1 * sp(ew[e*3+1])
                                 + c2 * sp(ew[e*3+2]);
    }

    #pragma unroll 1
    for (int l = 0; l < L; ++l) {
        const float* W  = ipw + l * 192;   // [24][8] row-major, wave-uniform
        const float* Bq = ipb + l * 24;

        v2f qp[E];
        if (active) {
            v2f qkv[24];
            #pragma unroll
            for (int jo = 0; jo < 24; ++jo) {
                v2f a = sp(Bq[jo]);
                #pragma unroll
                for (int e = 0; e < E; ++e) a += xr[e] * sp(W[jo*8 + e]);
                qkv[jo] = a;
            }
            #pragma unroll
            for (int c = 0; c < E; ++c) qp[c] = qkv[c] * QSCALE;
            if (pad) {   // row 67: k=0 (exp2(0)=1, fixed by lsum-1), v=0
                #pragma unroll
                for (int c = 8; c < 24; ++c) qkv[c].y = 0.f;
            }
            #pragma unroll
            for (int h = 0; h < H; ++h) {
                const int gh = g*2 + h;
                KA[gh][j] = make_float4(qkv[8+4*h+0].x, qkv[8+4*h+0].y,
                                        qkv[8+4*h+1].x, qkv[8+4*h+1].y);
                KB[gh][j] = make_float4(qkv[8+4*h+2].x, qkv[8+4*h+2].y,
                                        qkv[8+4*h+3].x, qkv[8+4*h+3].y);
                Vh[gh][j] = make_float4(
                    pkf(qkv[16+4*h+0].x, qkv[16+4*h+0].y),
                    pkf(qkv[16+4*h+1].x, qkv[16+4*h+1].y),
                    pkf(qkv[16+4*h+2].x, qkv[16+4*h+2].y),
                    pkf(qkv[16+4*h+3].x, qkv[16+4*h+3].y));
            }
        }
        __syncthreads();

        if (active) {
            v2f os[E];   // os[e] = {o[r0][e], o[r1][e]}
            #pragma unroll
            for (int h = 0; h < H; ++h) {
                const int gh = g*2 + h;
                const float4* pKA = KA[gh];
                const float4* pKB = KB[gh];
                const float4* pVh = Vh[gh];
                // row-specific q splats (low/high halves of qp)
                const v2f q0l = sp(qp[4*h+0].x), q0h = sp(qp[4*h+0].y);
                const v2f q1l = sp(qp[4*h+1].x), q1h = sp(qp[4*h+1].y);
                const v2f q2l = sp(qp[4*h+2].x), q2h = sp(qp[4*h+2].y);
                const v2f q3l = sp(qp[4*h+3].x), q3h = sp(qp[4*h+3].y);
                v2f ls0 = {0.f,0.f}, ls1 = {0.f,0.f};
                float oc00=0.f, oc01=0.f, oc02=0.f, oc03=0.f;
                float oc10=0.f, oc11=0.f, oc12=0.f, oc13=0.f;
                #pragma unroll
                for (int i = 0; i < NPAIR; ++i) {     // t = 0..67 (67 = zero-pad)
                    float4 ka = pKA[i], kb = pKB[i];
                    float4 vv = pVh[i];
                    v2f kx = *(const v2f*)&ka.x, ky = *(const v2f*)&ka.z;
                    v2f kz = *(const v2f*)&kb.x, kw = *(const v2f*)&kb.z;
                    v2f sc0 = q0l*kx + q1l*ky + q2l*kz + q3l*kw;   // row r0, {t0,t1}
                    v2f sc1 = q0h*kx + q1h*ky + q2h*kz + q3h*kw;   // row r1
                    v2f e0, e1;
                    e0.x = EXP2F(sc0.x);  e0.y = EXP2F(sc0.y);
                    e1.x = EXP2F(sc1.x);  e1.y = EXP2F(sc1.y);
                    ls0 += e0;  ls1 += e1;
                    h2 ep0 = cvh(e0.x, e0.y);    // row r0 e-weights, {t0,t1}
                    h2 ep1 = cvh(e1.x, e1.y);    // row r1
                    h2 v0 = bch(vv.x), v1 = bch(vv.y);
                    h2 v2 = bch(vv.z), v3 = bch(vv.w);
                    oc00 = FDOT2(ep0, v0, oc00); oc01 = FDOT2(ep0, v1, oc01);
                    oc02 = FDOT2(ep0, v2, oc02); oc03 = FDOT2(ep0, v3, oc03);
                    oc10 = FDOT2(ep1, v0, oc10); oc11 = FDOT2(ep1, v1, oc11);
                    oc12 = FDOT2(ep1, v2, oc12); oc13 = FDOT2(ep1, v3, oc13);
                }
                float l0 = ls0.x + ls0.y - 1.0f;   // remove pad's exp2(0)=1
                float l1 = ls1.x + ls1.y - 1.0f;
                float i0 = RCPF(l0), i1 = RCPF(l1);
                os[4*h+0] = (v2f){oc00*i0, oc10*i1};
                os[4*h+1] = (v2f){oc01*i0, oc11*i1};
                os[4*h+2] = (v2f){oc02*i0, oc12*i1};
                os[4*h+3] = (v2f){oc03*i0, oc13*i1};
            }

            // attn_out + residual + LN1
            {
                const float* WA = aow + l*64;   // [8][8]
                const float* BA = aob + l*8;
                #pragma unroll
                for (int e = 0; e < E; ++e) {
                    v2f a = sp(BA[e]);
                    #pragma unroll
                    for (int e2 = 0; e2 < E; ++e2) a += os[e2] * sp(WA[e*8 + e2]);
                    xr[e] += a;
                }
            }
            ln8p(xr, g1 + l*E, b1 + l*E);

            // FF
            {
                const float* W1 = f1w + l*128;  // [16][8]
                const float* B1 = f1b + l*16;
                const float* W2 = f2w + l*128;  // [8][16]
                const float* B2 = f2b + l*8;
                v2f t1[FF];
                #pragma unroll
                for (int f = 0; f < FF; ++f) {
                    v2f a = sp(B1[f]);
                    #pragma unroll
                    for (int e = 0; e < E; ++e) a += xr[e] * sp(W1[f*8 + e]);
                    a.x = fmaxf(a.x, 0.f);
                    a.y = fmaxf(a.y, 0.f);
                    t1[f] = a;
                }
                #pragma unroll
                for (int e = 0; e < E; ++e) {
                    v2f a = sp(B2[e]);
                    #pragma unroll
                    for (int f = 0; f < FF; ++f) a += t1[f] * sp(W2[e*16 + f]);
                    xr[e] += a;
                }
            }
            ln8p(xr, g2 + l*E, b2 + l*E);
        }
        __syncthreads();   // protect K/V before next layer overwrites
    }

    if (active) {
        float* dst = xf + (size_t)n * KF + r0 * E;   // rows 2j,2j+1 contiguous
        *(float4*)(dst + 0) = make_float4(xr[0].x, xr[1].x, xr[2].x, xr[3].x);
        *(float4*)(dst + 4) = make_float4(xr[4].x, xr[5].x, xr[6].x, xr[7].x);
        if (!pad) {
            *(float4*)(dst + 8)  = make_float4(xr[0].y, xr[1].y, xr[2].y, xr[3].y);
            *(float4*)(dst + 12) = make_float4(xr[4].y, xr[5].y, xr[6].y, xr[7].y);
        }
    }
}

// wt[k][c] = ow[c][k]
__global__ void tr_kernel(const float* __restrict__ ow, float* __restrict__ wt)
{
    int i = blockIdx.x * 256 + threadIdx.x;
    if (i < OUTC * KF) {
        int c = i / KF, k = i - c * KF;
        wt[k * OUTC + c] = ow[i];
    }
}

// out = tanh(Xf[32768,536] @ Wt[536,128] + b)
__global__ __launch_bounds__(256, 4)
void out_kernel(const float* __restrict__ xf, const float* __restrict__ wt,
                const float* __restrict__ ob, float* __restrict__ out)
{
    __shared__ float Xs[32][68];
    const int lid = threadIdx.x;
    const int tx  = lid & 31;
    const int ty  = lid >> 5;
    const int n0  = blockIdx.x * 32;

    float acc[4][4] = {};

    #pragma unroll 1
    for (int kc = 0; kc < 9; ++kc) {
        const int kb = kc * 64;
        const int kw = (kc < 8) ? 64 : 24;
        __syncthreads();
        const int nvec = 32 * (kw >> 2);
        for (int i = lid; i < nvec; i += 256) {
            int r = i / (kw >> 2), kq = i - r * (kw >> 2);
            *(float4*)&Xs[r][kq*4] =
                *(const float4*)&xf[(size_t)(n0 + r) * KF + kb + kq*4];
        }
        __syncthreads();
        #pragma unroll 4
        for (int k = 0; k < kw; ++k) {
            float4 w4 = *(const float4*)&wt[(size_t)(kb + k) * OUTC + tx*4];
            #pragma unroll
            for (int i = 0; i < 4; ++i) {
                float x = Xs[ty*4 + i][k];
                acc[i][0] += x*w4.x; acc[i][1] += x*w4.y;
                acc[i][2] += x*w4.z; acc[i][3] += x*w4.w;
            }
        }
    }

    const float4 bb = *(const float4*)&ob[tx*4];
    #pragma unroll
    for (int i = 0; i < 4; ++i) {
        int r = n0 + ty*4 + i;
        float4 v;
        v.x = tanhf(acc[i][0] + bb.x);
        v.y = tanhf(acc[i][1] + bb.y);
        v.z = tanhf(acc[i][2] + bb.z);
        v.w = tanhf(acc[i][3] + bb.w);
        *(float4*)(out + (size_t)r * OUTC + tx*4) = v;
    }
}

extern "C" void kernel_launch(void* const* d_in, const int* in_sizes, int n_in,
                              void* d_out, int out_size, void* d_ws, size_t ws_size,
                              hipStream_t stream) {
    (void)in_sizes; (void)n_in; (void)out_size; (void)ws_size;
    const float* pose = (const float*)d_in[0];
    const float* ew   = (const float*)d_in[1];
    const float* eb   = (const float*)d_in[2];
    const float* ipw  = (const float*)d_in[3];
    const float* ipb  = (const float*)d_in[4];
    const float* aow  = (const float*)d_in[5];
    const float* aob  = (const float*)d_in[6];
    const float* f1w  = (const float*)d_in[7];
    const float* f1b  = (const float*)d_in[8];
    const float* f2w  = (const float*)d_in[9];
    const float* f2b  = (const float*)d_in[10];
    const float* g1   = (const float*)d_in[11];
    const float* b1   = (const float*)d_in[12];
    const float* g2   = (const float*)d_in[13];
    const float* b2   = (const float*)d_in[14];
    const float* ow   = (const float*)d_in[15];
    const float* ob   = (const float*)d_in[16];

    float* xf = (float*)d_ws;                               // 70.25 MB
    float* wt = xf + (size_t)NTOT * KF;                     // 268 KB

    const int grid1 = (NTOT + EPB - 1) / EPB;               // 4682
    enc_kernel<<<grid1, THREADS, 0, stream>>>(pose, ew, eb, ipw, ipb, aow, aob,
                                              f1w, f1b, f2w, f2b, g1, b1, g2, b2, xf);
    tr_kernel<<<(OUTC*KF + 255)/256, 256, 0, stream>>>(ow, wt);
    out_kernel<<<NTOT / 32, 256, 0, stream>>>(xf, wt, ob, (float*)d_out);
}

// Round 8
// 1359.609 us; speedup vs baseline: 1.9508x; 1.1535x over previous
//
#include <hip/hip_runtime.h>
#include <math.h>

// Problem constants
#define NTOT 32768   // T*B
#define CIN  201
#define S    67      // keypoints (seq len)
#define E    8
#define H    2
#define L    12
#define FF   16
#define OUTC 128
#define KF   536     // S*E
#define EPB  7       // elements per block
#define LPE  34      // lanes per element; lane j owns rows 2j, 2j+1 (row 67 = pad)
#define THREADS 256  // 7*34 = 238 active (93%)
#define NPAIR 34     // t-pair slots; slot 33 = {t=66 real, t=67 zero-pad}

typedef float v2f __attribute__((ext_vector_type(2)));
typedef __fp16 h2  __attribute__((ext_vector_type(2)));

#if __has_builtin(__builtin_amdgcn_exp2f)
#define EXP2F(x) __builtin_amdgcn_exp2f(x)
#else
#define EXP2F(x) exp2f(x)
#endif
#if __has_builtin(__builtin_amdgcn_rcpf)
#define RCPF(x) __builtin_amdgcn_rcpf(x)
#else
#define RCPF(x) (1.0f/(x))
#endif
#if __has_builtin(__builtin_amdgcn_rsqf)
#define RSQF(x) __builtin_amdgcn_rsqf(x)
#else
#define RSQF(x) rsqrtf(x)
#endif

// f32 pair -> packed f16 pair (one v_cvt_pkrtz_f16_f32)
#if __has_builtin(__builtin_amdgcn_cvt_pkrtz)
__device__ __forceinline__ h2 cvh(float a, float b) {
    return __builtin_amdgcn_cvt_pkrtz(a, b);
}
#else
__device__ __forceinline__ h2 cvh(float a, float b) {
    h2 r; r.x = (__fp16)a; r.y = (__fp16)b; return r;
}
#endif
__device__ __forceinline__ float pkf(float a, float b) {
    return __builtin_bit_cast(float, cvh(a, b));
}
__device__ __forceinline__ h2 bch(float f) { return __builtin_bit_cast(h2, f); }

// fp32 += dot2(f16 pair, f16 pair): v_dot2_f32_f16, 2 MACs/instr
#if __has_builtin(__builtin_amdgcn_fdot2)
#define FDOT2(a, b, c) __builtin_amdgcn_fdot2((a), (b), (c), false)
#else
#define FDOT2(a, b, c) ((float)(a).x*(float)(b).x + (float)(a).y*(float)(b).y + (c))
#endif

// 0.5 (=1/sqrt(DH)) * log2(e)
#define QSCALE 0.7213475204444817f

__device__ __forceinline__ v2f sp(float x) { return (v2f){x, x}; }

__device__ __forceinline__ void ln8p(v2f* x, const float* __restrict__ gg,
                                     const float* __restrict__ bb) {
    v2f m = {0.f, 0.f};
    #pragma unroll
    for (int e = 0; e < E; ++e) m += x[e];
    m *= 0.125f;
    v2f v = {0.f, 0.f};
    #pragma unroll
    for (int e = 0; e < E; ++e) { v2f d = x[e] - m; v += d * d; }
    v *= 0.125f;
    v2f rs;
    rs.x = RSQF(v.x + 1e-5f);
    rs.y = RSQF(v.y + 1e-5f);
    #pragma unroll
    for (int e = 0; e < E; ++e) x[e] = (x[e] - m) * rs * sp(gg[e]) + sp(bb[e]);
}

// r0's f32 outer body + f16 LDS-resident K/V only (r1's proven layouts).
// LDS: Kh + Vh = 2 * 14 * 34 * 16 B = 15232 B -> 8 blocks/CU (thread cap).
// __launch_bounds__(256,6): cap ~85 regs -- the only cap proven spill-free
// (r1/r5/r6/r7 spilled at caps 64-73; r2 compiled clean at this bound).
__global__ __launch_bounds__(THREADS, 6)
void enc_kernel(const float* __restrict__ pose,
                const float* __restrict__ ew,  const float* __restrict__ ebias,
                const float* __restrict__ ipw, const float* __restrict__ ipb,
                const float* __restrict__ aow, const float* __restrict__ aob,
                const float* __restrict__ f1w, const float* __restrict__ f1b,
                const float* __restrict__ f2w, const float* __restrict__ f2b,
                const float* __restrict__ g1,  const float* __restrict__ b1,
                const float* __restrict__ g2,  const float* __restrict__ b2,
                float* __restrict__ xf)
{
    // Kh[gh][i] = {k01_t0, k23_t0, k01_t1, k23_t1}  (pairs over dims, per t)
    // Vh[gh][i] = {v0_{t0,t1}, v1_{t0,t1}, v2_{t0,t1}, v3_{t0,t1}} (pairs over t)
    __shared__ float4 Kh[EPB * H][NPAIR];
    __shared__ float4 Vh[EPB * H][NPAIR];

    const int lid = threadIdx.x;
    const int g   = lid / LPE;          // element in block (0..6 valid)
    const int j   = lid - g * LPE;      // pair index (0..33)
    const int n   = blockIdx.x * EPB + g;
    const bool active = (g < EPB) && (n < NTOT);
    const bool pad = (j == LPE - 1);    // lane 33: r1 = row 67 (doesn't exist)
    const int r0 = 2 * j;

    // ---- embed (rows r0=2j, r1=2j+1 packed into halves), f32 ----
    v2f xr[E];
    if (active) {
        const float* p0 = pose + (size_t)n * CIN + 3 * r0;
        const float* p1 = pad ? p0 : (p0 + 3);
        v2f c0 = {p0[0], p1[0]};
        v2f c1 = {p0[1], p1[1]};
        v2f c2 = {p0[2], p1[2]};
        #pragma unroll
        for (int e = 0; e < E; ++e)
            xr[e] = sp(ebias[e]) + c0 * sp(ew[e*3+0]) + c1 * sp(ew[e*3+1])
                                 + c2 * sp(ew[e*3+2]);
    }

    #pragma unroll 1
    for (int l = 0; l < L; ++l) {
        const float* W  = ipw + l * 192;   // [24][8] row-major, wave-uniform
        const float* Bq = ipb + l * 24;

        h2 qh[8];   // per head h: {q01_r0, q23_r0, q01_r1, q23_r1}
        if (active) {
            v2f qkv[24];
            #pragma unroll
            for (int jo = 0; jo < 24; ++jo) {
                v2f a = sp(Bq[jo]);
                #pragma unroll
                for (int e = 0; e < E; ++e) a += xr[e] * sp(W[jo*8 + e]);
                qkv[jo] = a;
            }
            if (pad) {   // row 67: k=0 (exp2(0)=1, fixed by lsum-1), v=0
                #pragma unroll
                for (int c = 8; c < 24; ++c) qkv[c].y = 0.f;
            }
            #pragma unroll
            for (int h = 0; h < H; ++h) {
                v2f q0 = qkv[4*h+0] * QSCALE, q1 = qkv[4*h+1] * QSCALE;
                v2f q2 = qkv[4*h+2] * QSCALE, q3 = qkv[4*h+3] * QSCALE;
                qh[4*h+0] = cvh(q0.x, q1.x);   // dims 0-1, row r0
                qh[4*h+1] = cvh(q2.x, q3.x);   // dims 2-3, row r0
                qh[4*h+2] = cvh(q0.y, q1.y);   // dims 0-1, row r1
                qh[4*h+3] = cvh(q2.y, q3.y);   // dims 2-3, row r1
                const int gh = g*2 + h;
                Kh[gh][j] = make_float4(
                    pkf(qkv[8+4*h+0].x, qkv[8+4*h+1].x),   // k01_t0
                    pkf(qkv[8+4*h+2].x, qkv[8+4*h+3].x),   // k23_t0
                    pkf(qkv[8+4*h+0].y, qkv[8+4*h+1].y),   // k01_t1
                    pkf(qkv[8+4*h+2].y, qkv[8+4*h+3].y));  // k23_t1
                Vh[gh][j] = make_float4(
                    pkf(qkv[16+4*h+0].x, qkv[16+4*h+0].y),
                    pkf(qkv[16+4*h+1].x, qkv[16+4*h+1].y),
                    pkf(qkv[16+4*h+2].x, qkv[16+4*h+2].y),
                    pkf(qkv[16+4*h+3].x, qkv[16+4*h+3].y));
            }
        }
        __syncthreads();

        if (active) {
            const h2 one2 = cvh(1.0f, 1.0f);
            v2f os[E];   // os[e] = {o[r0][e], o[r1][e]}
            #pragma unroll
            for (int h = 0; h < H; ++h) {
                const int gh = g*2 + h;
                const float4* pK = Kh[gh];
                const float4* pV = Vh[gh];
                const h2 q01_0 = qh[4*h+0], q23_0 = qh[4*h+1];
                const h2 q01_1 = qh[4*h+2], q23_1 = qh[4*h+3];
                float ls0 = 0.f, ls1 = 0.f;
                float oc00=0.f, oc01=0.f, oc02=0.f, oc03=0.f;
                float oc10=0.f, oc11=0.f, oc12=0.f, oc13=0.f;
                #pragma unroll
                for (int i = 0; i < NPAIR; ++i) {     // t = 0..67 (67 = zero-pad)
                    float4 kk = pK[i];
                    float4 vv = pV[i];
                    h2 ka = bch(kk.x), kb = bch(kk.y);   // t0: dims 01, 23
                    h2 kc = bch(kk.z), kd = bch(kk.w);   // t1: dims 01, 23
                    float s00 = FDOT2(q01_0, ka, FDOT2(q23_0, kb, 0.f));
                    float s01 = FDOT2(q01_0, kc, FDOT2(q23_0, kd, 0.f));
                    float s10 = FDOT2(q01_1, ka, FDOT2(q23_1, kb, 0.f));
                    float s11 = FDOT2(q01_1, kc, FDOT2(q23_1, kd, 0.f));
                    float e00 = EXP2F(s00), e01 = EXP2F(s01);
                    float e10 = EXP2F(s10), e11 = EXP2F(s11);
                    h2 ep0 = cvh(e00, e01);    // row r0, {t0,t1}
                    h2 ep1 = cvh(e10, e11);    // row r1
                    ls0 = FDOT2(ep0, one2, ls0);
                    ls1 = FDOT2(ep1, one2, ls1);
                    h2 v0 = bch(vv.x), v1 = bch(vv.y);
                    h2 v2 = bch(vv.z), v3 = bch(vv.w);
                    oc00 = FDOT2(ep0, v0, oc00); oc01 = FDOT2(ep0, v1, oc01);
                    oc02 = FDOT2(ep0, v2, oc02); oc03 = FDOT2(ep0, v3, oc03);
                    oc10 = FDOT2(ep1, v0, oc10); oc11 = FDOT2(ep1, v1, oc11);
                    oc12 = FDOT2(ep1, v2, oc12); oc13 = FDOT2(ep1, v3, oc13);
                }
                float l0 = ls0 - 1.0f;   // remove pad's exp2(0)=1
                float l1 = ls1 - 1.0f;
                float i0 = RCPF(l0), i1 = RCPF(l1);
                os[4*h+0] = (v2f){oc00*i0, oc10*i1};
                os[4*h+1] = (v2f){oc01*i0, oc11*i1};
                os[4*h+2] = (v2f){oc02*i0, oc12*i1};
                os[4*h+3] = (v2f){oc03*i0, oc13*i1};
            }

            // attn_out + residual + LN1 (f32, r0 exact)
            {
                const float* WA = aow + l*64;   // [8][8]
                const float* BA = aob + l*8;
                #pragma unroll
                for (int e = 0; e < E; ++e) {
                    v2f a = sp(BA[e]);
                    #pragma unroll
                    for (int e2 = 0; e2 < E; ++e2) a += os[e2] * sp(WA[e*8 + e2]);
                    xr[e] += a;
                }
            }
            ln8p(xr, g1 + l*E, b1 + l*E);

            // FF (f32, r0 exact)
            {
                const float* W1 = f1w + l*128;  // [16][8]
                const float* B1 = f1b + l*16;
                const float* W2 = f2w + l*128;  // [8][16]
                const float* B2 = f2b + l*8;
                v2f t1[FF];
                #pragma unroll
                for (int f = 0; f < FF; ++f) {
                    v2f a = sp(B1[f]);
                    #pragma unroll
                    for (int e = 0; e < E; ++e) a += xr[e] * sp(W1[f*8 + e]);
                    a.x = fmaxf(a.x, 0.f);
                    a.y = fmaxf(a.y, 0.f);
                    t1[f] = a;
                }
                #pragma unroll
                for (int e = 0; e < E; ++e) {
                    v2f a = sp(B2[e]);
                    #pragma unroll
                    for (int f = 0; f < FF; ++f) a += t1[f] * sp(W2[e*16 + f]);
                    xr[e] += a;
                }
            }
            ln8p(xr, g2 + l*E, b2 + l*E);
        }
        __syncthreads();   // protect K/V before next layer overwrites
    }

    if (active) {
        float* dst = xf + (size_t)n * KF + r0 * E;   // rows 2j,2j+1 contiguous
        *(float4*)(dst + 0) = make_float4(xr[0].x, xr[1].x, xr[2].x, xr[3].x);
        *(float4*)(dst + 4) = make_float4(xr[4].x, xr[5].x, xr[6].x, xr[7].x);
        if (!pad) {
            *(float4*)(dst + 8)  = make_float4(xr[0].y, xr[1].y, xr[2].y, xr[3].y);
            *(float4*)(dst + 12) = make_float4(xr[4].y, xr[5].y, xr[6].y, xr[7].y);
        }
    }
}

// wt[k][c] = ow[c][k]
__global__ void tr_kernel(const float* __restrict__ ow, float* __restrict__ wt)
{
    int i = blockIdx.x * 256 + threadIdx.x;
    if (i < OUTC * KF) {
        int c = i / KF, k = i - c * KF;
        wt[k * OUTC + c] = ow[i];
    }
}

// out = tanh(Xf[32768,536] @ Wt[536,128] + b)
__global__ __launch_bounds__(256, 4)
void out_kernel(const float* __restrict__ xf, const float* __restrict__ wt,
                const float* __restrict__ ob, float* __restrict__ out)
{
    __shared__ float Xs[32][68];
    const int lid = threadIdx.x;
    const int tx  = lid & 31;
    const int ty  = lid >> 5;
    const int n0  = blockIdx.x * 32;

    float acc[4][4] = {};

    #pragma unroll 1
    for (int kc = 0; kc < 9; ++kc) {
        const int kb = kc * 64;
        const int kw = (kc < 8) ? 64 : 24;
        __syncthreads();
        const int nvec = 32 * (kw >> 2);
        for (int i = lid; i < nvec; i += 256) {
            int r = i / (kw >> 2), kq = i - r * (kw >> 2);
            *(float4*)&Xs[r][kq*4] =
                *(const float4*)&xf[(size_t)(n0 + r) * KF + kb + kq*4];
        }
        __syncthreads();
        #pragma unroll 4
        for (int k = 0; k < kw; ++k) {
            float4 w4 = *(const float4*)&wt[(size_t)(kb + k) * OUTC + tx*4];
            #pragma unroll
            for (int i = 0; i < 4; ++i) {
                float x = Xs[ty*4 + i][k];
                acc[i][0] += x*w4.x; acc[i][1] += x*w4.y;
                acc[i][2] += x*w4.z; acc[i][3] += x*w4.w;
            }
        }
    }

    const float4 bb = *(const float4*)&ob[tx*4];
    #pragma unroll
    for (int i = 0; i < 4; ++i) {
        int r = n0 + ty*4 + i;
        float4 v;
        v.x = tanhf(acc[i][0] + bb.x);
        v.y = tanhf(acc[i][1] + bb.y);
        v.z = tanhf(acc[i][2] + bb.z);
        v.w = tanhf(acc[i][3] + bb.w);
        *(float4*)(out + (size_t)r * OUTC + tx*4) = v;
    }
}

extern "C" void kernel_launch(void* const* d_in, const int* in_sizes, int n_in,
                              void* d_out, int out_size, void* d_ws, size_t ws_size,
                              hipStream_t stream) {
    (void)in_sizes; (void)n_in; (void)out_size; (void)ws_size;
    const float* pose = (const float*)d_in[0];
    const float* ew   = (const float*)d_in[1];
    const float* eb   = (const float*)d_in[2];
    const float* ipw  = (const float*)d_in[3];
    const float* ipb  = (const float*)d_in[4];
    const float* aow  = (const float*)d_in[5];
    const float* aob  = (const float*)d_in[6];
    const float* f1w  = (const float*)d_in[7];
    const float* f1b  = (const float*)d_in[8];
    const float* f2w  = (const float*)d_in[9];
    const float* f2b  = (const float*)d_in[10];
    const float* g1   = (const float*)d_in[11];
    const float* b1   = (const float*)d_in[12];
    const float* g2   = (const float*)d_in[13];
    const float* b2   = (const float*)d_in[14];
    const float* ow   = (const float*)d_in[15];
    const float* ob   = (const float*)d_in[16];

    float* xf = (float*)d_ws;                               // 70.25 MB
    float* wt = xf + (size_t)NTOT * KF;                     // 268 KB

    const int grid1 = (NTOT + EPB - 1) / EPB;               // 4682
    enc_kernel<<<grid1, THREADS, 0, stream>>>(pose, ew, eb, ipw, ipb, aow, aob,
                                              f1w, f1b, f2w, f2b, g1, b1, g2, b2, xf);
    tr_kernel<<<(OUTC*KF + 255)/256, 256, 0, stream>>>(ow, wt);
    out_kernel<<<NTOT / 32, 256, 0, stream>>>(xf, wt, ob, (float*)d_out);
}